// Round 12
// baseline (1212.841 us; speedup 1.0000x reference)
//
#include <hip/hip_runtime.h>
#include <math.h>

#define NQ    8192     // N queries per batch
#define NP    8192     // M points per batch
#define NF    128      // feature dim
#define NOUT  512      // output dim
#define NB    2        // batches
#define KNN   10
#define BNQ   (NB*NQ)  // 16384 total queries
#define GC    16       // grid cells per axis
#define NCELL (GC*GC*GC/GC)   // 16*16 = rows; full cells = 4096
#define CELLS 4096

typedef unsigned long long u64;
typedef unsigned int u32;
typedef unsigned short ushort_t;
typedef __attribute__((ext_vector_type(8))) short bf16x8;
typedef __attribute__((ext_vector_type(4))) float f32x4;

// Normal quantile edges Phi^-1(i/16), i=1..15; cell c covers (E[c], E[c+1]].
__device__ const float EDGEX[17] = {
  -1e30f, -1.53412f, -1.15035f, -0.88715f, -0.67449f, -0.48878f, -0.31864f,
  -0.15731f, 0.0f, 0.15731f, 0.31864f, 0.48878f, 0.67449f, 0.88715f,
  1.15035f, 1.53412f, 1e30f };

__device__ __forceinline__ int bucket(float v) {
  int c = 0;
  c += (v > -1.53412f); c += (v > -1.15035f); c += (v > -0.88715f);
  c += (v > -0.67449f); c += (v > -0.48878f); c += (v > -0.31864f);
  c += (v > -0.15731f); c += (v > 0.0f);      c += (v > 0.15731f);
  c += (v > 0.31864f);  c += (v > 0.48878f);  c += (v > 0.67449f);
  c += (v > 0.88715f);  c += (v > 1.15035f);  c += (v > 1.53412f);
  return c;          // 0..15
}

// round-to-nearest-even f32 -> bf16
__device__ __forceinline__ ushort_t f2bf(float x) {
  unsigned u = __float_as_uint(x);
  return (ushort_t)((u + 0x7FFFu + ((u >> 16) & 1u)) >> 16);
}

// ---------------------------------------------------------------------------
// Prep: W -> bf16 Wb; zero the cell histogram.
// ---------------------------------------------------------------------------
__global__ __launch_bounds__(256) void prep_kernel(
    const float* __restrict__ W, ushort_t* __restrict__ Wb,
    int* __restrict__ hist)
{
  const int tid = blockIdx.x * 256 + threadIdx.x;   // 0..65535
  Wb[tid] = f2bf(W[tid]);
  if (tid < NB * CELLS) hist[tid] = 0;
}

// ---------------------------------------------------------------------------
// Histogram points per cell.
// ---------------------------------------------------------------------------
__global__ __launch_bounds__(256) void hist_kernel(
    const float* __restrict__ gpcd, int* __restrict__ hist)
{
  const int tid = blockIdx.x * 256 + threadIdx.x;   // 0..16383
  const float* p = gpcd + (size_t)tid * 3;
  const int cell = (bucket(p[0]) << 8) | (bucket(p[1]) << 4) | bucket(p[2]);
  atomicAdd(&hist[(tid >> 13) * CELLS + cell], 1);
}

// ---------------------------------------------------------------------------
// Exclusive scan of 2x4096 cell counts (segmented at the batch boundary).
// One block of 1024 threads, 8 cells/thread, Hillis-Steele over partials.
// ---------------------------------------------------------------------------
__global__ __launch_bounds__(1024) void scan_kernel(
    const int* __restrict__ hist, int* __restrict__ cellstart,
    int* __restrict__ cursor)
{
  __shared__ int tot[1024];
  const int t = threadIdx.x;
  int v[8]; int s = 0;
#pragma unroll
  for (int i = 0; i < 8; ++i) { v[i] = hist[t * 8 + i]; s += v[i]; }
  tot[t] = s;
  __syncthreads();
  int x = s;
  for (int off = 1; off < 1024; off <<= 1) {
    int y = 0;
    if (t >= off && ((t >= 512) == ((t - off) >= 512))) y = tot[t - off];
    __syncthreads();
    x += y; tot[t] = x;
    __syncthreads();
  }
  int run = x - s;                       // segment-local exclusive prefix
#pragma unroll
  for (int i = 0; i < 8; ++i) {
    const int cf = t * 8 + i;            // flat cell 0..8191
    const int b = cf >> 12, c = cf & (CELLS - 1);
    cellstart[b * (CELLS + 1) + c] = run;
    cursor[cf] = run;
    run += v[i];
  }
  if (t == 0) {
    cellstart[CELLS] = NP;
    cellstart[(CELLS + 1) + CELLS] = NP;
  }
}

// ---------------------------------------------------------------------------
// Scatter points into cell-sorted order; keep (x,y,z,p2) + original index.
// ---------------------------------------------------------------------------
__global__ __launch_bounds__(256) void scatter_kernel(
    const float* __restrict__ gpcd, int* __restrict__ cursor,
    float4* __restrict__ sortedPts, int* __restrict__ sortedIdx)
{
  const int tid = blockIdx.x * 256 + threadIdx.x;   // 0..16383
  const int b = tid >> 13, m = tid & 8191;
  const float* p = gpcd + (size_t)tid * 3;
  const float x = p[0], y = p[1], z = p[2];
  const int cell = (bucket(x) << 8) | (bucket(y) << 4) | bucket(z);
  const int pos = atomicAdd(&cursor[b * CELLS + cell], 1);
  sortedPts[(b << 13) + pos] = make_float4(x, y, z, x * x + y * y + z * z);
  sortedIdx[(b << 13) + pos] = m;
}

// ---------------------------------------------------------------------------
// Exact kNN, one lane per query. Expanding Chebyshev shells over the cell
// grid; per-lane register top-10 of u64 keys (mono(d2)<<32)|idx — exact
// lexicographic (d2, idx) order, independent of processing order (so the
// nondeterministic scatter order cannot change the result). Certification:
// stop when d2_10 <= m^2, m = min x-space distance to the unsearched region
// (EDGEX table consistent with bucket()). Shells are disjoint; s <= 15 ends.
// ---------------------------------------------------------------------------
__global__ __launch_bounds__(64) void knnq_kernel(
    const float* __restrict__ geometry,
    const float4* __restrict__ sortedPts, const int* __restrict__ sortedIdx,
    const int* __restrict__ cellstart,
    int* __restrict__ idxOut, float* __restrict__ wOut)
{
  const int q = blockIdx.x * 64 + threadIdx.x;      // 0..16383
  const int b = q >> 13;
  const float* g = geometry + (size_t)q * 3;
  const float qx = g[0], qy = g[1], qz = g[2];
  const float q2 = qx * qx + qy * qy + qz * qz;
  const float c2x = -2.f * qx, c2y = -2.f * qy, c2z = -2.f * qz;
  const int cx = bucket(qx), cy = bucket(qy), cz = bucket(qz);

  const float4* __restrict__ SP = sortedPts + ((size_t)b << 13);
  const int*    __restrict__ SI = sortedIdx + ((size_t)b << 13);
  const int*    __restrict__ CS = cellstart + b * (CELLS + 1);

  u64 l[KNN];
#pragma unroll
  for (int i = 0; i < KNN; ++i) l[i] = ~0ull;       // sentinel > any real key

  auto runcells = [&](int x, int y, int zlo, int zhi) {
    const int base = ((x << 4) | y) << 4;
    const int st = CS[base + zlo], en = CS[base + zhi + 1];
    for (int o = st; o < en; ++o) {
      const float4 p = SP[o];
      const int   id = SI[o];
      float d2 = fmaf(c2x, p.x, fmaf(c2y, p.y, fmaf(c2z, p.z, q2 + p.w)));
      d2 = fmaxf(d2, 0.f);
      const u64 kk = ((u64)(__float_as_uint(d2) | 0x80000000u) << 32) | (u32)id;
      if (kk < l[KNN - 1]) {
#pragma unroll
        for (int i = KNN - 1; i >= 1; --i)
          l[i] = (kk < l[i - 1]) ? l[i - 1] : ((kk < l[i]) ? kk : l[i]);
        l[0] = (kk < l[0]) ? kk : l[0];
      }
    }
  };

  int s = 0;
  for (;;) {
    if (s == 0) {
      runcells(cx, cy, cz, cz);
    } else {
      for (int dx = -s; dx <= s; ++dx) {
        const int x = cx + dx;
        if (x < 0 || x > 15) continue;
        const bool ex = (dx == -s) | (dx == s);
        for (int dy = -s; dy <= s; ++dy) {
          const int y = cy + dy;
          if (y < 0 || y > 15) continue;
          if (ex | (dy == -s) | (dy == s)) {
            runcells(x, y, max(cz - s, 0), min(cz + s, 15));
          } else {
            if (cz - s >= 0)  runcells(x, y, cz - s, cz - s);
            if (cz + s <= 15) runcells(x, y, cz + s, cz + s);
          }
        }
      }
    }
    // ---- certification ----
    const u32  hi    = (u32)(l[KNN - 1] >> 32);
    const float d2_10 = __uint_as_float(hi & 0x7fffffffu);  // NaN if underfull
    float m = fminf(qx - EDGEX[max(cx - s, 0)], EDGEX[min(cx + s + 1, 16)] - qx);
    m = fminf(m, fminf(qy - EDGEX[max(cy - s, 0)], EDGEX[min(cy + s + 1, 16)] - qy));
    m = fminf(m, fminf(qz - EDGEX[max(cz - s, 0)], EDGEX[min(cz + s + 1, 16)] - qz));
    if (d2_10 <= m * m || s >= 15) break;   // NaN <= x is false -> expand
    ++s;
  }

  // ---- normalized inverse-distance weights ----
  float w[KNN], wsum = 0.f;
#pragma unroll
  for (int j = 0; j < KNN; ++j) {
    const u32 hj = (u32)(l[j] >> 32);
    const float d2 = __uint_as_float(hj & 0x7fffffffu);
    w[j] = 1.f / (sqrtf(d2) + 1e-8f);
    wsum += w[j];
  }
#pragma unroll
  for (int j = 0; j < KNN; ++j) {
    idxOut[q * KNN + j] = (int)(u32)(l[j] & 0xffffffffu);
    wOut[q * KNN + j]   = w[j] / wsum;
  }
}

// ---------------------------------------------------------------------------
// Interp: gather 10 feature rows per query, weighted sum, bf16 A[q][128].
// Wave per 2 queries; lanes = feature pairs (coalesced float2 gathers).
// ---------------------------------------------------------------------------
__global__ __launch_bounds__(256) void interp_kernel(
    const float* __restrict__ features, const int* __restrict__ idxArr,
    const float* __restrict__ wArr, ushort_t* __restrict__ Abf)
{
  const int lane = threadIdx.x & 63;
  const int wave = (blockIdx.x << 2) | (threadIdx.x >> 6);
  const int q0 = wave << 1;
  const int b = q0 >> 13;
  const float* __restrict__ F = features + (size_t)b * NP * NF;
#pragma unroll
  for (int j = 0; j < 2; ++j) {
    const int q = q0 + j;
    float a0 = 0.f, a1 = 0.f;
#pragma unroll
    for (int jj = 0; jj < KNN; ++jj) {
      const int   mi = idxArr[q * KNN + jj];
      const float wj = wArr[q * KNN + jj];
      const float2 f2 = *(const float2*)(F + (size_t)mi * NF + (lane << 1));
      a0 = fmaf(wj, f2.x, a0);
      a1 = fmaf(wj, f2.y, a1);
    }
    unsigned pack = (unsigned)f2bf(a0) | ((unsigned)f2bf(a1) << 16);
    *(unsigned*)(Abf + (size_t)q * NF + (lane << 1)) = pack;
  }
}

// ---------------------------------------------------------------------------
// Stage C (MFMA, r9/r10-verified): out[q][o] = sum_f A[q][f]*Wb[o][f]+bias[o]
// ---------------------------------------------------------------------------
__global__ __launch_bounds__(256) void proj_mfma(
    const ushort_t* __restrict__ Abf, const ushort_t* __restrict__ Wb,
    const float* __restrict__ bias, float* __restrict__ out)
{
  const int lane = threadIdx.x & 63;
  const int w    = threadIdx.x >> 6;        // wave 0..3
  const int mt   = blockIdx.x & 127;        // 128 m-blocks
  const int ot   = blockIdx.x >> 7;         // 8 o-blocks
  const int m0   = (mt << 7) + ((w & 1) << 6);   // wave's 64-row band
  const int o0   = (ot << 6) + ((w >> 1) << 5);  // wave's 32-col band
  const int r    = lane & 15;
  const int kg   = (lane >> 4) << 3;        // k offset 0,8,16,24

  f32x4 acc[4][2];
#pragma unroll
  for (int i = 0; i < 4; ++i)
#pragma unroll
    for (int jn = 0; jn < 2; ++jn) acc[i][jn] = (f32x4)0.0f;

#pragma unroll
  for (int ks = 0; ks < 4; ++ks) {
    const int k0 = (ks << 5) + kg;
    bf16x8 a[4], bb[2];
#pragma unroll
    for (int i = 0; i < 4; ++i)
      a[i] = *(const bf16x8*)(Abf + (size_t)(m0 + (i << 4) + r) * NF + k0);
#pragma unroll
    for (int jn = 0; jn < 2; ++jn)
      bb[jn] = *(const bf16x8*)(Wb + (size_t)(o0 + (jn << 4) + r) * NF + k0);
#pragma unroll
    for (int i = 0; i < 4; ++i)
#pragma unroll
      for (int jn = 0; jn < 2; ++jn)
        acc[i][jn] = __builtin_amdgcn_mfma_f32_16x16x32_bf16(
            a[i], bb[jn], acc[i][jn], 0, 0, 0);
  }

  const int crow = (lane >> 4) << 2;
#pragma unroll
  for (int jn = 0; jn < 2; ++jn) {
    const int oc = o0 + (jn << 4) + r;
    const float bv = bias[oc];
#pragma unroll
    for (int i = 0; i < 4; ++i) {
#pragma unroll
      for (int reg = 0; reg < 4; ++reg) {
        const int qm = m0 + (i << 4) + crow + reg;
        out[(size_t)qm * NOUT + oc] = acc[i][jn][reg] + bv;
      }
    }
  }
}

// ---------------------------------------------------------------------------
extern "C" void kernel_launch(void* const* d_in, const int* in_sizes, int n_in,
                              void* d_out, int out_size, void* d_ws, size_t ws_size,
                              hipStream_t stream) {
  const float* geometry = (const float*)d_in[0];   // [2,8192,3]
  const float* gpcd     = (const float*)d_in[1];   // [2,8192,3]
  const float* features = (const float*)d_in[2];   // [2,8192,128]
  const float* W        = (const float*)d_in[3];   // [512,128]
  const float* bias     = (const float*)d_in[4];   // [512]
  float* out = (float*)d_out;

  // ws layout (16B-aligned blocks first); total ~6.1 MB
  char* ws = (char*)d_ws;
  size_t off = 0;
  ushort_t* Abf  = (ushort_t*)(ws + off); off += (size_t)BNQ * NF * 2;   // 4 MiB
  float4* sortedPts = (float4*)(ws + off); off += (size_t)NB * NP * 16;  // 256 KiB
  ushort_t* Wb   = (ushort_t*)(ws + off); off += (size_t)NOUT * NF * 2;  // 128 KiB
  int* hist      = (int*)(ws + off); off += (size_t)NB * CELLS * 4;
  int* cellstart = (int*)(ws + off); off += (size_t)NB * (CELLS + 1) * 4 + 8;
  int* cursor    = (int*)(ws + off); off += (size_t)NB * CELLS * 4;
  int* sortedIdx = (int*)(ws + off); off += (size_t)NB * NP * 4;
  int* idxOut    = (int*)(ws + off); off += (size_t)BNQ * KNN * 4;
  float* wOut    = (float*)(ws + off); off += (size_t)BNQ * KNN * 4;

  prep_kernel<<<256, 256, 0, stream>>>(W, Wb, hist);
  hist_kernel<<<64, 256, 0, stream>>>(gpcd, hist);
  scan_kernel<<<1, 1024, 0, stream>>>(hist, cellstart, cursor);
  scatter_kernel<<<64, 256, 0, stream>>>(gpcd, cursor, sortedPts, sortedIdx);
  knnq_kernel<<<BNQ / 64, 64, 0, stream>>>(geometry, sortedPts, sortedIdx,
                                           cellstart, idxOut, wOut);
  interp_kernel<<<BNQ / 8, 256, 0, stream>>>(features, idxOut, wOut, Abf);
  proj_mfma<<<(BNQ / 128) * (NOUT / 64), 256, 0, stream>>>(Abf, Wb, bias, out);
}

// Round 14
// 134.099 us; speedup vs baseline: 9.0444x; 9.0444x over previous
//
#include <hip/hip_runtime.h>
#include <math.h>

#define NQ    8192     // N queries per batch
#define NP    8192     // M points per batch
#define NF    128      // feature dim
#define NOUT  512      // output dim
#define NB    2        // batches
#define KNN   10
#define BNQ   (NB*NQ)  // 16384 total queries
#define CELLS 4096     // 16^3 grid

typedef unsigned long long u64;
typedef unsigned int u32;
typedef unsigned short ushort_t;
typedef __attribute__((ext_vector_type(8))) short bf16x8;
typedef __attribute__((ext_vector_type(4))) float f32x4;

// Normal quantile edges Phi^-1(i/16); cell c covers (E[c], E[c+1]].
__device__ const float EDGEX[17] = {
  -1e30f, -1.53412f, -1.15035f, -0.88715f, -0.67449f, -0.48878f, -0.31864f,
  -0.15731f, 0.0f, 0.15731f, 0.31864f, 0.48878f, 0.67449f, 0.88715f,
  1.15035f, 1.53412f, 1e30f };

__device__ __forceinline__ int bucket(float v) {
  int c = 0;
  c += (v > -1.53412f); c += (v > -1.15035f); c += (v > -0.88715f);
  c += (v > -0.67449f); c += (v > -0.48878f); c += (v > -0.31864f);
  c += (v > -0.15731f); c += (v > 0.0f);      c += (v > 0.15731f);
  c += (v > 0.31864f);  c += (v > 0.48878f);  c += (v > 0.67449f);
  c += (v > 0.88715f);  c += (v > 1.15035f);  c += (v > 1.53412f);
  return c;          // 0..15
}

__device__ __forceinline__ u64 shfl64(u64 v, int src) {
  unsigned lo = (unsigned)__shfl((int)(unsigned)(v & 0xffffffffull), src, 64);
  unsigned hi = (unsigned)__shfl((int)(unsigned)(v >> 32), src, 64);
  return ((u64)hi << 32) | lo;
}
__device__ __forceinline__ u64 shflup64(u64 v) {
  unsigned lo = (unsigned)__shfl_up((int)(unsigned)(v & 0xffffffffull), 1, 64);
  unsigned hi = (unsigned)__shfl_up((int)(unsigned)(v >> 32), 1, 64);
  return ((u64)hi << 32) | lo;
}

// Monotone f32->u32 bit map: mono(a) < mono(b) (unsigned) <=> a < b (float).
__device__ __forceinline__ unsigned fmono(float f) {
  unsigned u = __float_as_uint(f);
  return u ^ ((unsigned)((int)u >> 31) | 0x80000000u);
}
// nextafter(f, +inf) for finite f; +INF -> NaN (harmless in fminf).
__device__ __forceinline__ float nextupf(float f) {
  unsigned u = __float_as_uint(f);
  unsigned n = (u & 0x80000000u) ? ((u == 0x80000000u) ? 1u : u - 1u) : u + 1u;
  return __uint_as_float(n);
}

// r8-verified order-independent distributed insert: lanes 0..9 hold top-10
// u64 keys (mono(d2)<<32)|idx; threshold tracks nextup(dl[9]) so equal-d2
// candidates enter and the exact key compare places them (order-free).
// MUST be called with all 64 lanes active (shuffles need full exec).
__device__ __forceinline__ void insert_loop(float d2, int idxv, int lane,
                                            u64& lst, float& dlv, float& th) {
  for (;;) {
    u64 mask = __ballot(d2 < th);
    if (!mask) break;
    int src = __builtin_ctzll(mask);
    float cd = __uint_as_float(
        (unsigned)__builtin_amdgcn_readlane(__float_as_int(d2), src));
    int  ci = __builtin_amdgcn_readlane(idxv, src);
    u64 kk = ((u64)fmono(cd) << 32) | (u32)ci;
    u64   prev  = shflup64(lst);
    float prevd = __shfl(dlv, lane - 1, 64);
    bool mylt = lst < kk;
    bool pins = (lane == 0) || (prev < kk);
    lst = mylt ? lst : (pins ? kk : prev);
    dlv = mylt ? dlv : (pins ? cd : prevd);
    float d9 = __uint_as_float(
        (unsigned)__builtin_amdgcn_readlane(__float_as_int(dlv), 9));
    th = fminf(th, nextupf(d9));
    if (lane == src) d2 = __builtin_nanf("");
  }
}

// round-to-nearest-even f32 -> bf16
__device__ __forceinline__ ushort_t f2bf(float x) {
  unsigned u = __float_as_uint(x);
  return (ushort_t)((u + 0x7FFFu + ((u >> 16) & 1u)) >> 16);
}

// ---------------------------------------------------------------------------
// Prep: W -> bf16 Wb; zero the cell histogram.  (r12-verified)
// ---------------------------------------------------------------------------
__global__ __launch_bounds__(256) void prep_kernel(
    const float* __restrict__ W, ushort_t* __restrict__ Wb,
    int* __restrict__ hist)
{
  const int tid = blockIdx.x * 256 + threadIdx.x;
  Wb[tid] = f2bf(W[tid]);
  if (tid < NB * CELLS) hist[tid] = 0;
}

// ---------------------------------------------------------------------------
// Histogram points per cell.  (r12-verified)
// ---------------------------------------------------------------------------
__global__ __launch_bounds__(256) void hist_kernel(
    const float* __restrict__ gpcd, int* __restrict__ hist)
{
  const int tid = blockIdx.x * 256 + threadIdx.x;   // 0..16383
  const float* p = gpcd + (size_t)tid * 3;
  const int cell = (bucket(p[0]) << 8) | (bucket(p[1]) << 4) | bucket(p[2]);
  atomicAdd(&hist[(tid >> 13) * CELLS + cell], 1);
}

// ---------------------------------------------------------------------------
// Exclusive scan of 2x4096 cell counts (segmented).  (r12-verified)
// ---------------------------------------------------------------------------
__global__ __launch_bounds__(1024) void scan_kernel(
    const int* __restrict__ hist, int* __restrict__ cellstart,
    int* __restrict__ cursor)
{
  __shared__ int tot[1024];
  const int t = threadIdx.x;
  int v[8]; int s = 0;
#pragma unroll
  for (int i = 0; i < 8; ++i) { v[i] = hist[t * 8 + i]; s += v[i]; }
  tot[t] = s;
  __syncthreads();
  int x = s;
  for (int off = 1; off < 1024; off <<= 1) {
    int y = 0;
    if (t >= off && ((t >= 512) == ((t - off) >= 512))) y = tot[t - off];
    __syncthreads();
    x += y; tot[t] = x;
    __syncthreads();
  }
  int run = x - s;
#pragma unroll
  for (int i = 0; i < 8; ++i) {
    const int cf = t * 8 + i;
    const int b = cf >> 12, c = cf & (CELLS - 1);
    cellstart[b * (CELLS + 1) + c] = run;
    cursor[cf] = run;
    run += v[i];
  }
  if (t == 0) {
    cellstart[CELLS] = NP;
    cellstart[(CELLS + 1) + CELLS] = NP;
  }
}

// ---------------------------------------------------------------------------
// Scatter points into cell-sorted order.  (r12-verified)
// ---------------------------------------------------------------------------
__global__ __launch_bounds__(256) void scatter_kernel(
    const float* __restrict__ gpcd, int* __restrict__ cursor,
    float4* __restrict__ sortedPts, int* __restrict__ sortedIdx)
{
  const int tid = blockIdx.x * 256 + threadIdx.x;   // 0..16383
  const int b = tid >> 13, m = tid & 8191;
  const float* p = gpcd + (size_t)tid * 3;
  const float x = p[0], y = p[1], z = p[2];
  const int cell = (bucket(x) << 8) | (bucket(y) << 4) | bucket(z);
  const int pos = atomicAdd(&cursor[b * CELLS + cell], 1);
  sortedPts[(b << 13) + pos] = make_float4(x, y, z, x * x + y * y + z * z);
  sortedIdx[(b << 13) + pos] = m;
}

// ---------------------------------------------------------------------------
// Exact kNN + interp, ONE WAVE PER QUERY. Disjoint Chebyshev shells; lanes
// own cell-row segments; wave prefix-sum concatenates; candidates consumed
// in 64-wide batches through the r8-verified insert.
// FIX vs r13: the shuffle binary search runs with ALL lanes active (jc =
// min(j, total-1)); lanes beyond total NaN their d2 AFTER the load. CDNA
// ds_bpermute returns undefined data from EXEC-disabled source lanes, so
// shuffles must never sit inside the divergent branch (the r13 bug).
// ---------------------------------------------------------------------------
__global__ __launch_bounds__(256) void knn_interp_grid(
    const float* __restrict__ geometry,
    const float4* __restrict__ sortedPts, const int* __restrict__ sortedIdx,
    const int* __restrict__ cellstart, const float* __restrict__ features,
    ushort_t* __restrict__ Abf)
{
  const int lane = threadIdx.x & 63;
  const int q    = (blockIdx.x << 2) | (threadIdx.x >> 6);  // wave = query
  const int b    = q >> 13;

  const float* g = geometry + (size_t)q * 3;
  const float qx = g[0], qy = g[1], qz = g[2];
  const float q2 = qx * qx + qy * qy + qz * qz;
  const float c2x = -2.f * qx, c2y = -2.f * qy, c2z = -2.f * qz;
  const int cx = bucket(qx), cy = bucket(qy), cz = bucket(qz);

  const float4* __restrict__ SP = sortedPts + ((size_t)b << 13);
  const int*    __restrict__ SI = sortedIdx + ((size_t)b << 13);
  const int*    __restrict__ CS = cellstart + b * (CELLS + 1);

  u64   list = ~0ull;
  float dl   = INFINITY;
  float th   = INFINITY;

  for (int s = 0; s <= 15; ++s) {
    const int S = (s == 0) ? 1 : (8 * s + 2 * (2 * s - 1) * (2 * s - 1));
    for (int segbase = 0; segbase < S; segbase += 64) {
      const int k = segbase + lane;
      int st = 0, len = 0;
      if (k < S) {
        int x, y, zlo, zhi; bool valid;
        if (s == 0) {
          x = cx; y = cy; zlo = zhi = cz; valid = true;
        } else if (k < 8 * s) {
          const int twos = 2 * s;
          int side = 0, t = k;
          if (t >= twos) { ++side; t -= twos; }
          if (t >= twos) { ++side; t -= twos; }
          if (t >= twos) { ++side; t -= twos; }
          int dx, dy;
          if      (side == 0) { dx = -s + t; dy = -s; }
          else if (side == 1) { dx = s;      dy = -s + t; }
          else if (side == 2) { dx = s - t;  dy = s; }
          else                { dx = -s;     dy = s - t; }
          x = cx + dx; y = cy + dy;
          zlo = max(cz - s, 0); zhi = min(cz + s, 15);
          valid = (x >= 0) & (x < 16) & (y >= 0) & (y < 16);
        } else {
          const int kp = k - 8 * s;
          const int w  = 2 * s - 1;
          const int jj = kp >> 1;
          const int z  = (kp & 1) ? (cz + s) : (cz - s);
          x = cx - (s - 1) + (jj % w);
          y = cy - (s - 1) + (jj / w);
          zlo = zhi = z;
          valid = (x >= 0) & (x < 16) & (y >= 0) & (y < 16) & (z >= 0) & (z < 16);
        }
        if (valid) {
          const int base = ((x << 4) | y) << 4;
          st  = CS[base + zlo];
          len = CS[base + zhi + 1] - st;
        }
      }
      // exclusive prefix of len across the wave (full-exec shuffles)
      int pre = len;
#pragma unroll
      for (int off = 1; off < 64; off <<= 1) {
        int t2 = __shfl_up(pre, off, 64);
        if (lane >= off) pre += t2;
      }
      const int total = __shfl(pre, 63, 64);
      pre -= len;
      // consume candidates in 64-wide batches; ALL shuffles full-exec
      for (int cb = 0; cb < total; cb += 64) {
        const int j  = cb + lane;
        const int jc = min(j, total - 1);       // clamp: keep search valid
        int r = 0;                              // max r with pre[r] <= jc
#pragma unroll
        for (int off = 32; off; off >>= 1) {
          const int c = r + off;
          const int pc = __shfl(pre, c & 63, 64);
          if (c < 64 && pc <= jc) r = c;
        }
        const int o = __shfl(st, r, 64) + (jc - __shfl(pre, r, 64));
        const float4 p = SP[o];
        const int   idv = SI[o];
        float d2 = fmaf(c2x, p.x, fmaf(c2y, p.y, fmaf(c2z, p.z, q2 + p.w)));
        d2 = fmaxf(d2, 0.f);
        if (j >= total) d2 = __builtin_nanf("");   // mask AFTER the load
        insert_loop(d2, idv, lane, list, dl, th);
      }
    }
    // ---- certification (wave-uniform branch) ----
    const float d2_10 = __uint_as_float(
        (unsigned)__builtin_amdgcn_readlane(__float_as_int(dl), 9));
    float m = fminf(qx - EDGEX[max(cx - s, 0)], EDGEX[min(cx + s + 1, 16)] - qx);
    m = fminf(m, fminf(qy - EDGEX[max(cy - s, 0)], EDGEX[min(cy + s + 1, 16)] - qy));
    m = fminf(m, fminf(qz - EDGEX[max(cz - s, 0)], EDGEX[min(cz + s + 1, 16)] - qz));
    if (d2_10 <= m * m) break;          // INF/NaN compares false -> expand
  }

  // ---- weights + feature interpolation (r9/r10-verified tail) ----
  const float* __restrict__ F = features + (size_t)b * NP * NF;
  float w = 1.0f / (sqrtf(dl) + 1e-8f);          // meaningful on lanes 0..9
  float wsum = 0.0f;
#pragma unroll
  for (int jj = 0; jj < KNN; ++jj) wsum += __shfl(w, jj, 64);

  float a0 = 0.0f, a1 = 0.0f;
#pragma unroll
  for (int jj = 0; jj < KNN; ++jj) {
    float wj = __shfl(w, jj, 64) / wsum;
    int  mi  = (int)(u32)(shfl64(list, jj) & 0xffffffffull);
    const float2 f2 = *(const float2*)(F + (size_t)mi * NF + (lane << 1));
    a0 = fmaf(wj, f2.x, a0);
    a1 = fmaf(wj, f2.y, a1);
  }
  unsigned pack = (unsigned)f2bf(a0) | ((unsigned)f2bf(a1) << 16);
  *(unsigned*)(Abf + (size_t)q * NF + (lane << 1)) = pack;
}

// ---------------------------------------------------------------------------
// Stage C (MFMA, r9/r10-verified): out[q][o] = sum_f A[q][f]*Wb[o][f]+bias[o]
// ---------------------------------------------------------------------------
__global__ __launch_bounds__(256) void proj_mfma(
    const ushort_t* __restrict__ Abf, const ushort_t* __restrict__ Wb,
    const float* __restrict__ bias, float* __restrict__ out)
{
  const int lane = threadIdx.x & 63;
  const int w    = threadIdx.x >> 6;
  const int mt   = blockIdx.x & 127;
  const int ot   = blockIdx.x >> 7;
  const int m0   = (mt << 7) + ((w & 1) << 6);
  const int o0   = (ot << 6) + ((w >> 1) << 5);
  const int r    = lane & 15;
  const int kg   = (lane >> 4) << 3;

  f32x4 acc[4][2];
#pragma unroll
  for (int i = 0; i < 4; ++i)
#pragma unroll
    for (int jn = 0; jn < 2; ++jn) acc[i][jn] = (f32x4)0.0f;

#pragma unroll
  for (int ks = 0; ks < 4; ++ks) {
    const int k0 = (ks << 5) + kg;
    bf16x8 a[4], bb[2];
#pragma unroll
    for (int i = 0; i < 4; ++i)
      a[i] = *(const bf16x8*)(Abf + (size_t)(m0 + (i << 4) + r) * NF + k0);
#pragma unroll
    for (int jn = 0; jn < 2; ++jn)
      bb[jn] = *(const bf16x8*)(Wb + (size_t)(o0 + (jn << 4) + r) * NF + k0);
#pragma unroll
    for (int i = 0; i < 4; ++i)
#pragma unroll
      for (int jn = 0; jn < 2; ++jn)
        acc[i][jn] = __builtin_amdgcn_mfma_f32_16x16x32_bf16(
            a[i], bb[jn], acc[i][jn], 0, 0, 0);
  }

  const int crow = (lane >> 4) << 2;
#pragma unroll
  for (int jn = 0; jn < 2; ++jn) {
    const int oc = o0 + (jn << 4) + r;
    const float bv = bias[oc];
#pragma unroll
    for (int i = 0; i < 4; ++i) {
#pragma unroll
      for (int reg = 0; reg < 4; ++reg) {
        const int qm = m0 + (i << 4) + crow + reg;
        out[(size_t)qm * NOUT + oc] = acc[i][jn][reg] + bv;
      }
    }
  }
}

// ---------------------------------------------------------------------------
extern "C" void kernel_launch(void* const* d_in, const int* in_sizes, int n_in,
                              void* d_out, int out_size, void* d_ws, size_t ws_size,
                              hipStream_t stream) {
  const float* geometry = (const float*)d_in[0];   // [2,8192,3]
  const float* gpcd     = (const float*)d_in[1];   // [2,8192,3]
  const float* features = (const float*)d_in[2];   // [2,8192,128]
  const float* W        = (const float*)d_in[3];   // [512,128]
  const float* bias     = (const float*)d_in[4];   // [512]
  float* out = (float*)d_out;

  char* ws = (char*)d_ws;
  size_t off = 0;
  ushort_t* Abf  = (ushort_t*)(ws + off); off += (size_t)BNQ * NF * 2;   // 4 MiB
  float4* sortedPts = (float4*)(ws + off); off += (size_t)NB * NP * 16;  // 256 KiB
  ushort_t* Wb   = (ushort_t*)(ws + off); off += (size_t)NOUT * NF * 2;  // 128 KiB
  int* hist      = (int*)(ws + off); off += (size_t)NB * CELLS * 4;
  int* cellstart = (int*)(ws + off); off += (size_t)NB * (CELLS + 1) * 4 + 8;
  int* cursor    = (int*)(ws + off); off += (size_t)NB * CELLS * 4;
  int* sortedIdx = (int*)(ws + off); off += (size_t)NB * NP * 4;

  prep_kernel<<<256, 256, 0, stream>>>(W, Wb, hist);
  hist_kernel<<<64, 256, 0, stream>>>(gpcd, hist);
  scan_kernel<<<1, 1024, 0, stream>>>(hist, cellstart, cursor);
  scatter_kernel<<<64, 256, 0, stream>>>(gpcd, cursor, sortedPts, sortedIdx);
  knn_interp_grid<<<BNQ / 4, 256, 0, stream>>>(geometry, sortedPts, sortedIdx,
                                               cellstart, features, Abf);
  proj_mfma<<<(BNQ / 128) * (NOUT / 64), 256, 0, stream>>>(Abf, Wb, bias, out);
}

// Round 16
// 130.866 us; speedup vs baseline: 9.2678x; 1.0247x over previous
//
#include <hip/hip_runtime.h>
#include <math.h>

#define NQ    8192     // N queries per batch
#define NP    8192     // M points per batch
#define NF    128      // feature dim
#define NOUT  512      // output dim
#define NB    2        // batches
#define KNN   10
#define BNQ   (NB*NQ)  // 16384 total queries
#define CELLS 4096     // 16^3 grid

typedef unsigned long long u64;
typedef unsigned int u32;
typedef unsigned short ushort_t;
typedef __attribute__((ext_vector_type(8))) short bf16x8;
typedef __attribute__((ext_vector_type(4))) float f32x4;

// Normal quantile edges Phi^-1(i/16); cell c covers (E[c], E[c+1]].
__device__ const float EDGEX[17] = {
  -1e30f, -1.53412f, -1.15035f, -0.88715f, -0.67449f, -0.48878f, -0.31864f,
  -0.15731f, 0.0f, 0.15731f, 0.31864f, 0.48878f, 0.67449f, 0.88715f,
  1.15035f, 1.53412f, 1e30f };

__device__ __forceinline__ int bucket(float v) {
  int c = 0;
  c += (v > -1.53412f); c += (v > -1.15035f); c += (v > -0.88715f);
  c += (v > -0.67449f); c += (v > -0.48878f); c += (v > -0.31864f);
  c += (v > -0.15731f); c += (v > 0.0f);      c += (v > 0.15731f);
  c += (v > 0.31864f);  c += (v > 0.48878f);  c += (v > 0.67449f);
  c += (v > 0.88715f);  c += (v > 1.15035f);  c += (v > 1.53412f);
  return c;          // 0..15
}

__device__ __forceinline__ u64 shfl64(u64 v, int src) {
  unsigned lo = (unsigned)__shfl((int)(unsigned)(v & 0xffffffffull), src, 64);
  unsigned hi = (unsigned)__shfl((int)(unsigned)(v >> 32), src, 64);
  return ((u64)hi << 32) | lo;
}
__device__ __forceinline__ u64 shflup64(u64 v) {
  unsigned lo = (unsigned)__shfl_up((int)(unsigned)(v & 0xffffffffull), 1, 64);
  unsigned hi = (unsigned)__shfl_up((int)(unsigned)(v >> 32), 1, 64);
  return ((u64)hi << 32) | lo;
}

// Monotone f32->u32 bit map: mono(a) < mono(b) (unsigned) <=> a < b (float).
__device__ __forceinline__ unsigned fmono(float f) {
  unsigned u = __float_as_uint(f);
  return u ^ ((unsigned)((int)u >> 31) | 0x80000000u);
}
// nextafter(f, +inf) for finite f; +INF/NaN -> NaN (harmless in fminf).
__device__ __forceinline__ float nextupf(float f) {
  unsigned u = __float_as_uint(f);
  unsigned n = (u & 0x80000000u) ? ((u == 0x80000000u) ? 1u : u - 1u) : u + 1u;
  return __uint_as_float(n);
}

__device__ __forceinline__ float wmin64f(float v) {
#pragma unroll
  for (int off = 1; off < 64; off <<= 1)
    v = fminf(v, __shfl_xor(v, off, 64));
  return v;   // broadcast min across all 64 lanes (r5-verified)
}

// r8-verified order-independent distributed insert (full-exec only).
__device__ __forceinline__ void insert_loop(float d2, int idxv, int lane,
                                            u64& lst, float& dlv, float& th) {
  for (;;) {
    u64 mask = __ballot(d2 < th);
    if (!mask) break;
    int src = __builtin_ctzll(mask);
    float cd = __uint_as_float(
        (unsigned)__builtin_amdgcn_readlane(__float_as_int(d2), src));
    int  ci = __builtin_amdgcn_readlane(idxv, src);
    u64 kk = ((u64)fmono(cd) << 32) | (u32)ci;
    u64   prev  = shflup64(lst);
    float prevd = __shfl(dlv, lane - 1, 64);
    bool mylt = lst < kk;
    bool pins = (lane == 0) || (prev < kk);
    lst = mylt ? lst : (pins ? kk : prev);
    dlv = mylt ? dlv : (pins ? cd : prevd);
    float d9 = __uint_as_float(
        (unsigned)__builtin_amdgcn_readlane(__float_as_int(dlv), 9));
    th = fminf(th, nextupf(d9));
    if (lane == src) d2 = __builtin_nanf("");
  }
}

// round-to-nearest-even f32 -> bf16
__device__ __forceinline__ ushort_t f2bf(float x) {
  unsigned u = __float_as_uint(x);
  return (ushort_t)((u + 0x7FFFu + ((u >> 16) & 1u)) >> 16);
}

// ---------------------------------------------------------------------------
// Prep: W -> bf16 Wb; zero the cell histogram.  (r12-verified)
// ---------------------------------------------------------------------------
__global__ __launch_bounds__(256) void prep_kernel(
    const float* __restrict__ W, ushort_t* __restrict__ Wb,
    int* __restrict__ hist)
{
  const int tid = blockIdx.x * 256 + threadIdx.x;
  Wb[tid] = f2bf(W[tid]);
  if (tid < NB * CELLS) hist[tid] = 0;
}

// ---------------------------------------------------------------------------
// Histogram points per cell.  (r12-verified)
// ---------------------------------------------------------------------------
__global__ __launch_bounds__(256) void hist_kernel(
    const float* __restrict__ gpcd, int* __restrict__ hist)
{
  const int tid = blockIdx.x * 256 + threadIdx.x;   // 0..16383
  const float* p = gpcd + (size_t)tid * 3;
  const int cell = (bucket(p[0]) << 8) | (bucket(p[1]) << 4) | bucket(p[2]);
  atomicAdd(&hist[(tid >> 13) * CELLS + cell], 1);
}

// ---------------------------------------------------------------------------
// Exclusive scan of 2x4096 cell counts (segmented).  (r12-verified)
// ---------------------------------------------------------------------------
__global__ __launch_bounds__(1024) void scan_kernel(
    const int* __restrict__ hist, int* __restrict__ cellstart,
    int* __restrict__ cursor)
{
  __shared__ int tot[1024];
  const int t = threadIdx.x;
  int v[8]; int s = 0;
#pragma unroll
  for (int i = 0; i < 8; ++i) { v[i] = hist[t * 8 + i]; s += v[i]; }
  tot[t] = s;
  __syncthreads();
  int x = s;
  for (int off = 1; off < 1024; off <<= 1) {
    int y = 0;
    if (t >= off && ((t >= 512) == ((t - off) >= 512))) y = tot[t - off];
    __syncthreads();
    x += y; tot[t] = x;
    __syncthreads();
  }
  int run = x - s;
#pragma unroll
  for (int i = 0; i < 8; ++i) {
    const int cf = t * 8 + i;
    const int b = cf >> 12, c = cf & (CELLS - 1);
    cellstart[b * (CELLS + 1) + c] = run;
    cursor[cf] = run;
    run += v[i];
  }
  if (t == 0) {
    cellstart[CELLS] = NP;
    cellstart[(CELLS + 1) + CELLS] = NP;
  }
}

// ---------------------------------------------------------------------------
// Scatter points into cell-sorted order.  (r12-verified)
// ---------------------------------------------------------------------------
__global__ __launch_bounds__(256) void scatter_kernel(
    const float* __restrict__ gpcd, int* __restrict__ cursor,
    float4* __restrict__ sortedPts, int* __restrict__ sortedIdx)
{
  const int tid = blockIdx.x * 256 + threadIdx.x;   // 0..16383
  const int b = tid >> 13, m = tid & 8191;
  const float* p = gpcd + (size_t)tid * 3;
  const float x = p[0], y = p[1], z = p[2];
  const int cell = (bucket(x) << 8) | (bucket(y) << 4) | bucket(z);
  const int pos = atomicAdd(&cursor[b * CELLS + cell], 1);
  sortedPts[(b << 13) + pos] = make_float4(x, y, z, x * x + y * y + z * z);
  sortedIdx[(b << 13) + pos] = m;
}

// ---------------------------------------------------------------------------
// Exact kNN + interp, ONE WAVE PER QUERY (r14-verified structure).
// r15's bitonic merge REVERTED (failed; bisecting). Kept from r15:
//  (a) shell 0 folded into shell 1 (extra center segment),
//  (b) cap div/mod via magic multiply.
// NEW (verified parts only): first non-empty batch seeds th via the
// r5-verified tau-knockout (10 x wmin64f+ballot) => insert flood shrinks
// from ~25-35 to ~10-13 serial iterations; insert_loop itself unchanged.
// ---------------------------------------------------------------------------
__global__ __launch_bounds__(256) void knn_interp_grid(
    const float* __restrict__ geometry,
    const float4* __restrict__ sortedPts, const int* __restrict__ sortedIdx,
    const int* __restrict__ cellstart, const float* __restrict__ features,
    ushort_t* __restrict__ Abf)
{
  const int lane = threadIdx.x & 63;
  const int q    = (blockIdx.x << 2) | (threadIdx.x >> 6);  // wave = query
  const int b    = q >> 13;

  const float* g = geometry + (size_t)q * 3;
  const float qx = g[0], qy = g[1], qz = g[2];
  const float q2 = qx * qx + qy * qy + qz * qz;
  const float c2x = -2.f * qx, c2y = -2.f * qy, c2z = -2.f * qz;
  const int cx = bucket(qx), cy = bucket(qy), cz = bucket(qz);

  const float4* __restrict__ SP = sortedPts + ((size_t)b << 13);
  const int*    __restrict__ SI = sortedIdx + ((size_t)b << 13);
  const int*    __restrict__ CS = cellstart + b * (CELLS + 1);

  u64   list = ~0ull;
  float dl   = INFINITY;
  float th   = INFINITY;
  bool  firstbatch = true;

  for (int s = 1; s <= 15; ++s) {
    const int w20 = 2 * s - 1;
    const u32 Mw  = (0x100000u + (u32)w20 - 1) / (u32)w20;   // ceil(2^20/w)
    const int Scap = 8 * s + 2 * w20 * w20;
    const int S = Scap + (s == 1 ? 1 : 0);
    for (int segbase = 0; segbase < S; segbase += 64) {
      const int k = segbase + lane;
      int st = 0, len = 0;
      if (k < S) {
        int x, y, zlo, zhi; bool valid;
        if (k < 8 * s) {
          const int twos = 2 * s;
          int side = 0, t = k;
          if (t >= twos) { ++side; t -= twos; }
          if (t >= twos) { ++side; t -= twos; }
          if (t >= twos) { ++side; t -= twos; }
          int dx, dy;
          if      (side == 0) { dx = -s + t; dy = -s; }
          else if (side == 1) { dx = s;      dy = -s + t; }
          else if (side == 2) { dx = s - t;  dy = s; }
          else                { dx = -s;     dy = s - t; }
          x = cx + dx; y = cy + dy;
          zlo = max(cz - s, 0); zhi = min(cz + s, 15);
          valid = (x >= 0) & (x < 16) & (y >= 0) & (y < 16);
        } else if (k < Scap) {
          const int kp = k - 8 * s;
          const u32 jj = (u32)(kp >> 1);
          const int z  = (kp & 1) ? (cz + s) : (cz - s);
          const u32 qd = (jj * Mw) >> 20;          // jj / w (exact, jj<841)
          const u32 rm = jj - qd * (u32)w20;       // jj % w
          x = cx - (s - 1) + (int)rm;
          y = cy - (s - 1) + (int)qd;
          zlo = zhi = z;
          valid = (x >= 0) & (x < 16) & (y >= 0) & (y < 16) & (z >= 0) & (z < 16);
        } else {                                   // center cell (s==1 only)
          x = cx; y = cy; zlo = zhi = cz; valid = true;
        }
        if (valid) {
          const int base = ((x << 4) | y) << 4;
          st  = CS[base + zlo];
          len = CS[base + zhi + 1] - st;
        }
      }
      // exclusive prefix of len across the wave (full-exec shuffles)
      int pre = len;
#pragma unroll
      for (int off = 1; off < 64; off <<= 1) {
        int t2 = __shfl_up(pre, off, 64);
        if (lane >= off) pre += t2;
      }
      const int total = __shfl(pre, 63, 64);
      pre -= len;
      // consume candidates in 64-wide batches; ALL shuffles full-exec (r14 fix)
      for (int cb = 0; cb < total; cb += 64) {
        const int j  = cb + lane;
        const int jc = min(j, total - 1);
        int r = 0;
#pragma unroll
        for (int off = 32; off; off >>= 1) {
          const int c = r + off;
          const int pc = __shfl(pre, c & 63, 64);
          if (c < 64 && pc <= jc) r = c;
        }
        const int o = __shfl(st, r, 64) + (jc - __shfl(pre, r, 64));
        const float4 p = SP[o];
        const int   idv = SI[o];
        float d2 = fmaf(c2x, p.x, fmaf(c2y, p.y, fmaf(c2z, p.z, q2 + p.w)));
        d2 = fmaxf(d2, 0.f);
        if (j >= total) d2 = __builtin_nanf("");   // mask AFTER the load

        if (firstbatch) {
          // r5-verified tau-knockout: tau = 10th-smallest batch candidate
          // (NaN padding drops out of fminf and the == ballot).
          float lm = d2;
          float tau = INFINITY;
#pragma unroll
          for (int r2 = 0; r2 < KNN; ++r2) {
            tau = wmin64f(lm);
            u64 mk = __ballot(lm == tau);
            int w2 = __builtin_ctzll(mk);
            if (lane == w2) lm = INFINITY;
          }
          th = fminf(th, nextupf(tau));   // admit ties at tau; exact via keys
          firstbatch = false;
        }
        insert_loop(d2, idv, lane, list, dl, th);
      }
    }
    // ---- certification (wave-uniform branch) ----
    const float d2_10 = __uint_as_float(
        (unsigned)__builtin_amdgcn_readlane(__float_as_int(dl), 9));
    float m = fminf(qx - EDGEX[max(cx - s, 0)], EDGEX[min(cx + s + 1, 16)] - qx);
    m = fminf(m, fminf(qy - EDGEX[max(cy - s, 0)], EDGEX[min(cy + s + 1, 16)] - qy));
    m = fminf(m, fminf(qz - EDGEX[max(cz - s, 0)], EDGEX[min(cz + s + 1, 16)] - qz));
    if (d2_10 <= m * m) break;          // INF/NaN compares false -> expand
  }

  // ---- weights + feature interpolation (r9/r10-verified tail) ----
  const float* __restrict__ F = features + (size_t)b * NP * NF;
  float w = 1.0f / (sqrtf(dl) + 1e-8f);          // meaningful on lanes 0..9
  float wsum = 0.0f;
#pragma unroll
  for (int jj = 0; jj < KNN; ++jj) wsum += __shfl(w, jj, 64);

  float a0 = 0.0f, a1 = 0.0f;
#pragma unroll
  for (int jj = 0; jj < KNN; ++jj) {
    float wj = __shfl(w, jj, 64) / wsum;
    int  mi  = (int)(u32)(shfl64(list, jj) & 0xffffffffull);
    const float2 f2 = *(const float2*)(F + (size_t)mi * NF + (lane << 1));
    a0 = fmaf(wj, f2.x, a0);
    a1 = fmaf(wj, f2.y, a1);
  }
  unsigned pack = (unsigned)f2bf(a0) | ((unsigned)f2bf(a1) << 16);
  *(unsigned*)(Abf + (size_t)q * NF + (lane << 1)) = pack;
}

// ---------------------------------------------------------------------------
// Stage C (MFMA, r9/r10-verified): out[q][o] = sum_f A[q][f]*Wb[o][f]+bias[o]
// ---------------------------------------------------------------------------
__global__ __launch_bounds__(256) void proj_mfma(
    const ushort_t* __restrict__ Abf, const ushort_t* __restrict__ Wb,
    const float* __restrict__ bias, float* __restrict__ out)
{
  const int lane = threadIdx.x & 63;
  const int w    = threadIdx.x >> 6;
  const int mt   = blockIdx.x & 127;
  const int ot   = blockIdx.x >> 7;
  const int m0   = (mt << 7) + ((w & 1) << 6);
  const int o0   = (ot << 6) + ((w >> 1) << 5);
  const int r    = lane & 15;
  const int kg   = (lane >> 4) << 3;

  f32x4 acc[4][2];
#pragma unroll
  for (int i = 0; i < 4; ++i)
#pragma unroll
    for (int jn = 0; jn < 2; ++jn) acc[i][jn] = (f32x4)0.0f;

#pragma unroll
  for (int ks = 0; ks < 4; ++ks) {
    const int k0 = (ks << 5) + kg;
    bf16x8 a[4], bb[2];
#pragma unroll
    for (int i = 0; i < 4; ++i)
      a[i] = *(const bf16x8*)(Abf + (size_t)(m0 + (i << 4) + r) * NF + k0);
#pragma unroll
    for (int jn = 0; jn < 2; ++jn)
      bb[jn] = *(const bf16x8*)(Wb + (size_t)(o0 + (jn << 4) + r) * NF + k0);
#pragma unroll
    for (int i = 0; i < 4; ++i)
#pragma unroll
      for (int jn = 0; jn < 2; ++jn)
        acc[i][jn] = __builtin_amdgcn_mfma_f32_16x16x32_bf16(
            a[i], bb[jn], acc[i][jn], 0, 0, 0);
  }

  const int crow = (lane >> 4) << 2;
#pragma unroll
  for (int jn = 0; jn < 2; ++jn) {
    const int oc = o0 + (jn << 4) + r;
    const float bv = bias[oc];
#pragma unroll
    for (int i = 0; i < 4; ++i) {
#pragma unroll
      for (int reg = 0; reg < 4; ++reg) {
        const int qm = m0 + (i << 4) + crow + reg;
        out[(size_t)qm * NOUT + oc] = acc[i][jn][reg] + bv;
      }
    }
  }
}

// ---------------------------------------------------------------------------
extern "C" void kernel_launch(void* const* d_in, const int* in_sizes, int n_in,
                              void* d_out, int out_size, void* d_ws, size_t ws_size,
                              hipStream_t stream) {
  const float* geometry = (const float*)d_in[0];   // [2,8192,3]
  const float* gpcd     = (const float*)d_in[1];   // [2,8192,3]
  const float* features = (const float*)d_in[2];   // [2,8192,128]
  const float* W        = (const float*)d_in[3];   // [512,128]
  const float* bias     = (const float*)d_in[4];   // [512]
  float* out = (float*)d_out;

  char* ws = (char*)d_ws;
  size_t off = 0;
  ushort_t* Abf  = (ushort_t*)(ws + off); off += (size_t)BNQ * NF * 2;   // 4 MiB
  float4* sortedPts = (float4*)(ws + off); off += (size_t)NB * NP * 16;  // 256 KiB
  ushort_t* Wb   = (ushort_t*)(ws + off); off += (size_t)NOUT * NF * 2;  // 128 KiB
  int* hist      = (int*)(ws + off); off += (size_t)NB * CELLS * 4;
  int* cellstart = (int*)(ws + off); off += (size_t)NB * (CELLS + 1) * 4 + 8;
  int* cursor    = (int*)(ws + off); off += (size_t)NB * CELLS * 4;
  int* sortedIdx = (int*)(ws + off); off += (size_t)NB * NP * 4;

  prep_kernel<<<256, 256, 0, stream>>>(W, Wb, hist);
  hist_kernel<<<64, 256, 0, stream>>>(gpcd, hist);
  scan_kernel<<<1, 1024, 0, stream>>>(hist, cellstart, cursor);
  scatter_kernel<<<64, 256, 0, stream>>>(gpcd, cursor, sortedPts, sortedIdx);
  knn_interp_grid<<<BNQ / 4, 256, 0, stream>>>(geometry, sortedPts, sortedIdx,
                                               cellstart, features, Abf);
  proj_mfma<<<(BNQ / 128) * (NOUT / 64), 256, 0, stream>>>(Abf, Wb, bias, out);
}